// Round 17
// baseline (273.525 us; speedup 1.0000x reference)
//
#include <hip/hip_runtime.h>
#include <stdint.h>

#define T_ 4096
#define D_ 1024
#define F_ 4096
#define E_ 8
#define NCAT 8448   // 4096 (gate) + 4096 (up) + 256 (2*A1cat | 2*A3cat rows)
#define KH 4224     // hsum K (4096) + route-expanded Q (128)
#define NTILE_MAX 320

typedef __attribute__((ext_vector_type(8))) short          s16x8;
typedef __attribute__((ext_vector_type(8))) unsigned short u16x8;
typedef __attribute__((ext_vector_type(4))) unsigned short u16x4;
typedef __attribute__((ext_vector_type(4))) float          f32x4;

__device__ __forceinline__ unsigned short f2bf(float f) {
  unsigned u = __float_as_uint(f);
  u += 0x7fffu + ((u >> 16) & 1u);   // round-to-nearest-even
  return (unsigned short)(u >> 16);
}
__device__ __forceinline__ float b2f(unsigned short h) {
  return __uint_as_float(((unsigned)h) << 16);
}

// ---------------------------------------------------------------- convert
__device__ __forceinline__ void cvt8(const float* __restrict__ s, unsigned short* __restrict__ d) {
  float4 a = *(const float4*)s;
  float4 b = *(const float4*)(s + 4);
  u16x8 v;
  v[0] = f2bf(a.x); v[1] = f2bf(a.y); v[2] = f2bf(a.z); v[3] = f2bf(a.w);
  v[4] = f2bf(b.x); v[5] = f2bf(b.y); v[6] = f2bf(b.z); v[7] = f2bf(b.w);
  *(u16x8*)d = v;
}
__device__ __forceinline__ void cvt8s2(const float* __restrict__ s, unsigned short* __restrict__ d) {
  float4 a = *(const float4*)s;
  float4 b = *(const float4*)(s + 4);
  u16x8 v;
  v[0] = f2bf(2.f * a.x); v[1] = f2bf(2.f * a.y); v[2] = f2bf(2.f * a.z); v[3] = f2bf(2.f * a.w);
  v[4] = f2bf(2.f * b.x); v[5] = f2bf(2.f * b.y); v[6] = f2bf(2.f * b.z); v[7] = f2bf(2.f * b.w);
  *(u16x8*)d = v;
}

__global__ __launch_bounds__(256) void conv_kernel(
    const float* __restrict__ x,  const float* __restrict__ W1,
    const float* __restrict__ W3, const float* __restrict__ W2,
    const float* __restrict__ A1, const float* __restrict__ A3,
    const float* __restrict__ B1, const float* __restrict__ B3,
    const float* __restrict__ A2, const float* __restrict__ B2,
    unsigned short* __restrict__ xb,  unsigned short* __restrict__ Wcatb,
    unsigned short* __restrict__ W2cat, unsigned short* __restrict__ B1b,
    unsigned short* __restrict__ B3b, unsigned short* __restrict__ A2r) {
  const int y = blockIdx.y;
  const size_t i0 = ((size_t)blockIdx.x * 256 + threadIdx.x) * 8;
  if (y == 0) { cvt8(x + i0, xb + i0); }
  else if (y == 1) {
    // W2 [1024][4096] -> W2cat rows of stride 4224 (cols 0..4095)
    const size_t d = i0 >> 12, f = i0 & 4095;
    cvt8(W2 + i0, W2cat + d * KH + f);
  }
  else if (y == 2) { cvt8(W1 + i0, Wcatb + i0); }
  else if (y == 3) { cvt8(W3 + i0, Wcatb + 4194304 + i0); }
  else {
    // small tensors, 8-wide. SCALE=2 folded into A-matrices. 245760 groups of 8.
    const size_t o8 = (size_t)blockIdx.x * 256 + threadIdx.x;
    if (o8 < 245760) {
      const size_t o = o8 * 8;
      if (o < 131072)        cvt8s2(A1 + o, Wcatb + 8388608 + o);
      else if (o < 262144)   cvt8s2(A3 + (o - 131072), Wcatb + 8388608 + o);
      else if (o < 786432)   cvt8(B1 + (o - 262144), B1b + (o - 262144));
      else if (o < 1310720)  cvt8(B3 + (o - 786432), B3b + (o - 786432));
      else if (o < 1835008)  cvt8s2(A2 + (o - 1310720), A2r + (o - 1310720)); // [E][16][F]
      else {
        // B2cat: W2cat[d][4096 + e*16 + r] = B2[e][d][r]  (plain, no scale)
        const size_t oo = o - 1835008;              // 131072 = 1024*128
        const size_t d = oo >> 7, j = oo & 127;
        const size_t e = j >> 4, r0 = j & 15;       // r0 in {0,8}
        cvt8(B2 + e * ((size_t)D_ * 16) + d * 16 + r0, W2cat + d * KH + 4096 + j);
      }
    }
  }
}

// ---------------------------------------------------------------- router
__global__ __launch_bounds__(256) void router_kernel(
    const float* __restrict__ x, const float* __restrict__ gw,
    float* __restrict__ logits, int2* __restrict__ topi, float2* __restrict__ topw) {
  const int wave = threadIdx.x >> 6, lane = threadIdx.x & 63;
  const int t = blockIdx.x * 4 + wave;
  const float* xr = x + (size_t)t * D_;
  float acc[E_] = {0, 0, 0, 0, 0, 0, 0, 0};
  for (int it = 0; it < 16; ++it) {
    const int d = lane + it * 64;
    const float xv = xr[d];
#pragma unroll
    for (int e = 0; e < E_; ++e) acc[e] += xv * gw[e * D_ + d];
  }
#pragma unroll
  for (int e = 0; e < E_; ++e)
#pragma unroll
    for (int m = 1; m < 64; m <<= 1) acc[e] += __shfl_xor(acc[e], m);
  if (lane == 0) {
    float m0v = acc[0]; int m0i = 0;
#pragma unroll
    for (int e = 1; e < E_; ++e) if (acc[e] > m0v) { m0v = acc[e]; m0i = e; }
    float m1v = -3.0e38f; int m1i = 0;
#pragma unroll
    for (int e = 0; e < E_; ++e) if (e != m0i && acc[e] > m1v) { m1v = acc[e]; m1i = e; }
    const float e1 = __expf(m1v - m0v);
    const float inv = 1.f / (1.f + e1);
    topi[t] = make_int2(m0i, m1i);
    topw[t] = make_float2(inv, e1 * inv);
#pragma unroll
    for (int e = 0; e < E_; ++e) logits[(size_t)t * E_ + e] = acc[e];
  }
}

// ---------------------------------------------------------------- pair buckets
__global__ __launch_bounds__(256) void bucket_kernel(
    const int2* __restrict__ topi, int* __restrict__ bucketTok, int* __restrict__ bucketCnt) {
  const int pid = blockIdx.x;
  const int e0 = pid >> 3, e1 = pid & 7;
  __shared__ int cnt;
  if (threadIdx.x == 0) cnt = 0;
  __syncthreads();
  for (int t = threadIdx.x; t < T_; t += 256) {
    const int2 ti = topi[t];
    if (ti.x == e0 && ti.y == e1) {
      const int s = atomicAdd(&cnt, 1);
      bucketTok[pid * T_ + s] = t;
    }
  }
  __syncthreads();
  if (threadIdx.x == 0) bucketCnt[pid] = cnt;
}

// ---------------------------------------------------------------- compact tile worklist (wave prefix scan)
__global__ void tilelist_kernel(const int* __restrict__ bucketCnt, int* __restrict__ tileList) {
  const int pid = threadIdx.x;  // 64 threads, 1 wave
  const int ntile = (bucketCnt[pid] + 15) >> 4;
  int scan = ntile;
#pragma unroll
  for (int m = 1; m < 64; m <<= 1) {
    const int v = __shfl_up(scan, m);
    if (pid >= m) scan += v;
  }
  const int base = scan - ntile;
  const int total = __shfl(scan, 63);
  for (int i = 0; i < ntile; ++i) tileList[base + i] = (pid << 16) | i;
  for (int i = total + pid; i < NTILE_MAX; i += 64) tileList[i] = -1;
}

__device__ __forceinline__ void cstore(float* C, size_t i, float v) { C[i] = v; }
__device__ __forceinline__ void cstore(unsigned short* C, size_t i, float v) { C[i] = f2bf(v); }

#define GLL(g, l) __builtin_amdgcn_global_load_lds(                            \
    (const __attribute__((address_space(1))) void*)(g),                       \
    (__attribute__((address_space(3))) void*)(l), 16, 0, 0)

// ---------------------------------------------------------------- gemm1: 128x128, BK=64, TRIPLE-buffered LDS,
// prefetch depth 2, counted boundary wait vmcnt(8) (loads stay in flight across barriers).
// Compute body is byte-identical to the proven 2-phase gemm_bt<128>.
__global__ __launch_bounds__(256) void gemm1_3b(
    const unsigned short* __restrict__ A, const unsigned short* __restrict__ B,
    unsigned short* __restrict__ C, int M, int N, int K, int nbx) {
  __shared__ __align__(16) char LDS[3 * 32768];   // per buf: A 16KB @0, B 16KB @16384
  const int tid = threadIdx.x;
  int bid = blockIdx.x;
  bid = (bid & 7) * (gridDim.x >> 3) + (bid >> 3);  // XCD swizzle (grid %8==0)
  const int bx = bid % nbx, by = bid / nbx;
  const long m0 = (long)bx * 128, n0 = (long)by * 128;

  const unsigned short* asrc[4];
  const unsigned short* bsrc[4];
#pragma unroll
  for (int i = 0; i < 4; ++i) {
    const int g = i * 256 + tid, row = g >> 3, cb = (g & 7) ^ (row & 7);
    asrc[i] = A + (m0 + row) * (size_t)K + cb * 8;
    bsrc[i] = B + (n0 + row) * (size_t)K + cb * 8;
  }
  const int lane = tid & 63, wave = tid >> 6;
  const int wr = wave >> 1, wc = wave & 1;
  const int wb = (tid & 192) * 16;
  int aoff[4][2], boff[4][2];
#pragma unroll
  for (int mf = 0; mf < 4; ++mf) {
    const int ra = wr * 64 + mf * 16 + (lane & 15);
    const int rb = wc * 64 + mf * 16 + (lane & 15);
#pragma unroll
    for (int ks = 0; ks < 2; ++ks) {
      const int kb = (ks * 32 + (lane >> 4) * 8) * 2;
      aoff[mf][ks] = (ra * 128 + kb) ^ ((ra & 7) << 4);
      boff[mf][ks] = 16384 + ((rb * 128 + kb) ^ ((rb & 7) << 4));
    }
  }

  auto STAGE = [&](int buf, int kt) {
    const size_t ko = (size_t)kt * 64;
#pragma unroll
    for (int i = 0; i < 4; ++i) GLL(asrc[i] + ko, LDS + buf * 32768 + i * 4096 + wb);
#pragma unroll
    for (int i = 0; i < 4; ++i) GLL(bsrc[i] + ko, LDS + buf * 32768 + 16384 + i * 4096 + wb);
  };

  f32x4 acc[4][4] = {};
  const int nk = K >> 6;
  // prologue: stage tiles 0 and 1 (8 loads each); vmcnt(8) = tile 0 landed
  STAGE(0, 0);
  STAGE(1, 1);
  asm volatile("s_waitcnt vmcnt(8)" ::: "memory");
  __builtin_amdgcn_s_barrier();
  for (int kt = 0; kt < nk; ++kt) {
    if (kt + 2 < nk) STAGE((kt + 2) % 3, kt + 2);   // depth-2 prefetch, stays in flight
    const char* Ab = LDS + (kt % 3) * 32768;
#pragma unroll
    for (int ks = 0; ks < 2; ++ks) {
      s16x8 af[4], bfv[4];
#pragma unroll
      for (int mf = 0; mf < 4; ++mf) af[mf] = *(const s16x8*)(Ab + aoff[mf][ks]);
#pragma unroll
      for (int nf = 0; nf < 4; ++nf) bfv[nf] = *(const s16x8*)(Ab + boff[nf][ks]);
#pragma unroll
      for (int mf = 0; mf < 4; ++mf)
#pragma unroll
        for (int nf = 0; nf < 4; ++nf)
          acc[mf][nf] = __builtin_amdgcn_mfma_f32_16x16x32_bf16(af[mf], bfv[nf], acc[mf][nf], 0, 0, 0);
    }
    if (kt + 1 < nk) {
      // wait for tile kt+1's 8 loads (older); keep tile kt+2's 8 in flight
      if (kt + 2 < nk) asm volatile("s_waitcnt vmcnt(8)" ::: "memory");
      else             asm volatile("s_waitcnt vmcnt(0)" ::: "memory");
      __builtin_amdgcn_s_barrier();
    }
  }
#pragma unroll
  for (int mf = 0; mf < 4; ++mf) {
    const int row0 = (int)m0 + wr * 64 + mf * 16 + ((lane >> 4) << 2);
#pragma unroll
    for (int nf = 0; nf < 4; ++nf) {
      const long col = n0 + wc * 64 + nf * 16 + (lane & 15);
#pragma unroll
      for (int q = 0; q < 4; ++q)
        cstore(C, (size_t)(row0 + q) * N + col, acc[mf][nf][q]);
    }
  }
}

// ---------------------------------------------------------------- GEMM: 2-phase double-buffered (proven; used for gemm2)
// Optional K-split via blockIdx.z (Kstride = row stride, ksub = per-z K chunk).
template <int BN, typename OUT_T>
__global__ __launch_bounds__(256) void gemm_bt(
    const unsigned short* __restrict__ A, const unsigned short* __restrict__ B,
    OUT_T* __restrict__ C, int M, int N, int Kstride, int ksub, int nbx) {
  constexpr int WCOL = BN / 2, NF = WCOL / 16;
  constexpr int BITER = BN / 32;
  __shared__ __align__(16) char As[2 * 16384];
  __shared__ __align__(16) char Bs[2 * BN * 128];
  const int tid = threadIdx.x;
  int bid = blockIdx.x;
  bid = (bid & 7) * (gridDim.x >> 3) + (bid >> 3);  // XCD swizzle (grid %8==0)
  const int bx = bid % nbx, by = bid / nbx;
  const long m0 = (long)bx * 128, n0 = (long)by * BN;
  const int k0 = blockIdx.z * ksub;
  C += (size_t)blockIdx.z * M * N;                  // K-split partial strip

  const unsigned short* asrc[4];
  const unsigned short* bsrc[BITER];
#pragma unroll
  for (int i = 0; i < 4; ++i) {
    const int g = i * 256 + tid, row = g >> 3, cb = (g & 7) ^ (row & 7);
    asrc[i] = A + (m0 + row) * (size_t)Kstride + k0 + cb * 8;
  }
#pragma unroll
  for (int i = 0; i < BITER; ++i) {
    const int g = i * 256 + tid, row = g >> 3, cb = (g & 7) ^ (row & 7);
    bsrc[i] = B + (n0 + row) * (size_t)Kstride + k0 + cb * 8;
  }
  const int lane = tid & 63, wave = tid >> 6;
  const int wr = wave >> 1, wc = wave & 1;
  const int wb = (tid & 192) * 16;
  int aoff[4][2], boff[NF][2];
#pragma unroll
  for (int mf = 0; mf < 4; ++mf) {
    const int ra = wr * 64 + mf * 16 + (lane & 15);
#pragma unroll
    for (int ks = 0; ks < 2; ++ks) {
      const int kb = (ks * 32 + (lane >> 4) * 8) * 2;
      aoff[mf][ks] = (ra * 128 + kb) ^ ((ra & 7) << 4);
    }
  }
#pragma unroll
  for (int nf = 0; nf < NF; ++nf) {
    const int rb = wc * WCOL + nf * 16 + (lane & 15);
#pragma unroll
    for (int ks = 0; ks < 2; ++ks) {
      const int kb = (ks * 32 + (lane >> 4) * 8) * 2;
      boff[nf][ks] = (rb * 128 + kb) ^ ((rb & 7) << 4);
    }
  }

  auto STAGE = [&](int buf, int kt) {
    const size_t ko = (size_t)kt * 64;
#pragma unroll
    for (int i = 0; i < 4; ++i) GLL(asrc[i] + ko, As + buf * 16384 + i * 4096 + wb);
#pragma unroll
    for (int i = 0; i < BITER; ++i) GLL(bsrc[i] + ko, Bs + buf * (BN * 128) + i * 4096 + wb);
  };

  f32x4 acc[4][NF] = {};
  const int nk = ksub >> 6;
  int cur = 0;
  STAGE(0, 0);
  asm volatile("s_waitcnt vmcnt(0)" ::: "memory");
  __builtin_amdgcn_s_barrier();
  for (int kt = 0; kt < nk; ++kt) {
    if (kt + 1 < nk) STAGE(cur ^ 1, kt + 1);
    const char* Ab = As + cur * 16384;
    const char* Bb = Bs + cur * (BN * 128);
#pragma unroll
    for (int ks = 0; ks < 2; ++ks) {
      s16x8 af[4], bfv[NF];
#pragma unroll
      for (int mf = 0; mf < 4; ++mf) af[mf] = *(const s16x8*)(Ab + aoff[mf][ks]);
#pragma unroll
      for (int nf = 0; nf < NF; ++nf) bfv[nf] = *(const s16x8*)(Bb + boff[nf][ks]);
#pragma unroll
      for (int mf = 0; mf < 4; ++mf)
#pragma unroll
        for (int nf = 0; nf < NF; ++nf)
          acc[mf][nf] = __builtin_amdgcn_mfma_f32_16x16x32_bf16(af[mf], bfv[nf], acc[mf][nf], 0, 0, 0);
    }
    asm volatile("s_waitcnt vmcnt(0)" ::: "memory");
    __builtin_amdgcn_s_barrier();
    cur ^= 1;
  }
#pragma unroll
  for (int mf = 0; mf < 4; ++mf) {
    const int row0 = (int)m0 + wr * 64 + mf * 16 + ((lane >> 4) << 2);
#pragma unroll
    for (int nf = 0; nf < NF; ++nf) {
      const long col = n0 + wc * WCOL + nf * 16 + (lane & 15);
#pragma unroll
      for (int q = 0; q < 4; ++q)
        cstore(C, (size_t)(row0 + q) * N + col, acc[mf][nf][q]);
    }
  }
}

// ---------------------------------------------------------------- s3d: fused SwiGLU + LoRA-B + q-contraction (operand-swapped MFMA)
__global__ __launch_bounds__(256) void s3d_kernel(
    const unsigned short* __restrict__ xguP,  // [T, NCAT]
    const unsigned short* __restrict__ B1b,   // [E][F][16] bf16
    const unsigned short* __restrict__ B3b,   // [E][F][16] bf16
    const unsigned short* __restrict__ A2r,   // [E][16][F] bf16 (pre-scaled 2x)
    const int* __restrict__ bucketTok, const int* __restrict__ bucketCnt,
    const float2* __restrict__ topw, const int* __restrict__ tileList,
    unsigned short* __restrict__ hq,          // [T][KH] bf16 (cols 0..4095 = hsum)
    float* __restrict__ Qpart) {              // [16][T][32]  (strip = quarter*4 + wave)
  const int entry = tileList[blockIdx.x];
  if (entry < 0) return;
  const int pid = entry >> 16, z = entry & 0xffff;
  const int nt = bucketCnt[pid];
  const int e0 = pid >> 3, e1 = pid & 7;

  __shared__ int   ldsTok[16];
  __shared__ float ldsW[2][16];
  __shared__ __align__(16) unsigned short hwT[4][2][16][40];  // [wave][expert][token][f pad 32->40]
  const int tid = threadIdx.x;
  if (tid < 16) {
    int s = z * 16 + tid; if (s >= nt) s = nt - 1;
    const int t = bucketTok[pid * T_ + s];
    ldsTok[tid] = t;
    const float2 w = topw[t];
    ldsW[0][tid] = w.x; ldsW[1][tid] = w.y;
  }
  __syncthreads();

  const int lane = tid & 63, wave = tid >> 6;
  const int col = lane & 15, chunk = lane >> 4;

  const int t = ldsTok[col];
  const float w0 = ldsW[0][col], w1 = ldsW[1][col];
  const unsigned short* abase = xguP + (size_t)t * NCAT + 8192 +
                                (chunk >> 1) * 128 + (chunk & 1) * 8;
  const s16x8 afrag0 = *(const s16x8*)(abase + e0 * 16);
  const s16x8 afrag1 = *(const s16x8*)(abase + e1 * 16);

  unsigned short (*hw_w)[16][40] = hwT[wave];
  f32x4 qacc0 = {}, qacc1 = {};
  const int ft0 = blockIdx.y * 64 + wave * 16;   // 16 f-tiles per wave

  for (int p = 0; p < 8; ++p) {                  // pairs of 16-f subtiles (K=32 for q-MFMA)
#pragma unroll
    for (int half = 0; half < 2; ++half) {
      const int i = p * 2 + half;
      const int fcol = (ft0 + i) * 16 + col;     // A-operand (B1/B3) row = f position = lane&15
      s16x8 bg0 = {}, bu0 = {}, bg1 = {}, bu1 = {};
      if (chunk < 2) {
        bg0 = *(const s16x8*)(B1b + ((size_t)e0 * F_ + fcol) * 16 + chunk * 8);
        bg1 = *(const s16x8*)(B1b + ((size_t)e1 * F_ + fcol) * 16 + chunk * 8);
      } else {
        bu0 = *(const s16x8*)(B3b + ((size_t)e0 * F_ + fcol) * 16 + (chunk - 2) * 8);
        bu1 = *(const s16x8*)(B3b + ((size_t)e1 * F_ + fcol) * 16 + (chunk - 2) * 8);
      }
      f32x4 accg0 = {}, accu0 = {}, accg1 = {}, accu1 = {};
      accg0 = __builtin_amdgcn_mfma_f32_16x16x32_bf16(bg0, afrag0, accg0, 0, 0, 0);
      accu0 = __builtin_amdgcn_mfma_f32_16x16x32_bf16(bu0, afrag0, accu0, 0, 0, 0);
      accg1 = __builtin_amdgcn_mfma_f32_16x16x32_bf16(bg1, afrag1, accg1, 0, 0, 0);
      accu1 = __builtin_amdgcn_mfma_f32_16x16x32_bf16(bu1, afrag1, accu1, 0, 0, 0);

      const int fbase = (ft0 + i) * 16 + chunk * 4;   // 4 consecutive f for q=0..3
      const u16x4 xgv = *(const u16x4*)(xguP + (size_t)t * NCAT + fbase);
      const u16x4 xuv = *(const u16x4*)(xguP + (size_t)t * NCAT + 4096 + fbase);
      u16x4 hqv, h0v, h1v;
#pragma unroll
      for (int q = 0; q < 4; ++q) {
        const float xg = b2f(xgv[q]);
        const float xu = b2f(xuv[q]);
        const float g0 = xg + accg0[q], u0 = xu + accu0[q];
        const float g1 = xg + accg1[q], u1 = xu + accu1[q];
        const float h0 = g0 * u0 * __builtin_amdgcn_rcpf(1.f + __expf(-g0));  // silu via rcp (~1ulp)
        const float h1 = g1 * u1 * __builtin_amdgcn_rcpf(1.f + __expf(-g1));
        const unsigned short hb0 = f2bf(w0 * h0);
        const unsigned short hb1 = f2bf(w1 * h1);
        h0v[q] = hb0; h1v[q] = hb1;
        hqv[q] = f2bf(b2f(hb0) + b2f(hb1));
      }
      *(u16x4*)(hq + (size_t)t * KH + fbase) = hqv;
      *(u16x4*)&hw_w[0][col][half * 16 + chunk * 4] = h0v;  // LDS transpose stage
      *(u16x4*)&hw_w[1][col][half * 16 + chunk * 4] = h1v;
    }
    // wave-private region: writes above -> reads below (RAW via lgkmcnt; DS in-order per wave)
    asm volatile("s_waitcnt lgkmcnt(0)" ::: "memory");
    const s16x8 hf0 = *(const s16x8*)&hw_w[0][lane & 15][(lane >> 4) * 8];
    const s16x8 hf1 = *(const s16x8*)&hw_w[1][lane & 15][(lane >> 4) * 8];
    const int fb = (ft0 + 2 * p) * 16 + (lane >> 4) * 8;
    const s16x8 a2f0 = *(const s16x8*)(A2r + ((size_t)e0 * 16 + (lane & 15)) * F_ + fb);
    const s16x8 a2f1 = *(const s16x8*)(A2r + ((size_t)e1 * 16 + (lane & 15)) * F_ + fb);
    qacc0 = __builtin_amdgcn_mfma_f32_16x16x32_bf16(hf0, a2f0, qacc0, 0, 0, 0);
    qacc1 = __builtin_amdgcn_mfma_f32_16x16x32_bf16(hf1, a2f1, qacc1, 0, 0, 0);
  }

  const int r = lane & 15;
  float* qp = Qpart + ((size_t)blockIdx.y * 4 + wave) * T_ * 32;
#pragma unroll
  for (int q = 0; q < 4; ++q) {
    const int tq = ldsTok[chunk * 4 + q];
    qp[(size_t)tq * 32 + r]      = qacc0[q];
    qp[(size_t)tq * 32 + 16 + r] = qacc1[q];
  }
}

// ---------------------------------------------------------------- qscatter: hq[t][4096+j] = route-expanded sum of Qpart strips
__global__ __launch_bounds__(256) void qscatter_kernel(
    const float* __restrict__ Qpart, const int2* __restrict__ topi,
    unsigned short* __restrict__ hq) {
  const int gid = blockIdx.x * 256 + threadIdx.x;   // 524288 = T * 128
  const int t = gid >> 7, j = gid & 127;
  const int2 ti = topi[t];
  const int eb = j >> 4, r = j & 15;
  float v = 0.f;
  if (eb == ti.x) {
#pragma unroll
    for (int st = 0; st < 16; ++st) v += Qpart[(size_t)st * (T_ * 32) + t * 32 + r];
  } else if (eb == ti.y) {
#pragma unroll
    for (int st = 0; st < 16; ++st) v += Qpart[(size_t)st * (T_ * 32) + t * 32 + 16 + r];
  }
  hq[(size_t)t * KH + 4096 + j] = f2bf(v);
}

// ---------------------------------------------------------------- sum2: out = Opart[0] + Opart[1]  (float4)
__global__ __launch_bounds__(256) void sum2_kernel(const float* __restrict__ Op,
                                                   float* __restrict__ out) {
  const size_t i = ((size_t)blockIdx.x * 256 + threadIdx.x) * 4;
  const float4 a = *(const float4*)(Op + i);
  const float4 b = *(const float4*)(Op + (size_t)T_ * D_ + i);
  float4 o;
  o.x = a.x + b.x; o.y = a.y + b.y; o.z = a.z + b.z; o.w = a.w + b.w;
  *(float4*)(out + i) = o;
}

// ---------------------------------------------------------------- launcher
extern "C" void kernel_launch(void* const* d_in, const int* in_sizes, int n_in,
                              void* d_out, int out_size, void* d_ws, size_t ws_size,
                              hipStream_t stream) {
  (void)in_sizes; (void)n_in; (void)out_size; (void)ws_size;
  const float* x   = (const float*)d_in[0];
  const float* gw  = (const float*)d_in[1];
  const float* W1  = (const float*)d_in[2];
  const float* W3  = (const float*)d_in[3];
  const float* W2  = (const float*)d_in[4];
  const float* A1  = (const float*)d_in[5];
  const float* B1  = (const float*)d_in[6];
  const float* A3  = (const float*)d_in[7];
  const float* B3  = (const float*)d_in[8];
  const float* A2  = (const float*)d_in[9];
  const float* B2  = (const float*)d_in[10];
  float* out = (float*)d_out;
  float* logits = out + (size_t)T_ * D_;

  char* w = (char*)d_ws;
  auto alloc = [&](size_t bytes) { char* p = w; w += (bytes + 255) & ~(size_t)255; return p; };
  unsigned short* xb    = (unsigned short*)alloc((size_t)T_ * D_ * 2);
  unsigned short* Wcatb = (unsigned short*)alloc((size_t)NCAT * D_ * 2);
  unsigned short* W2cat = (unsigned short*)alloc((size_t)D_ * KH * 2);
  unsigned short* B1b   = (unsigned short*)alloc((size_t)E_ * F_ * 16 * 2);
  unsigned short* B3b   = (unsigned short*)alloc((size_t)E_ * F_ * 16 * 2);
  unsigned short* A2r   = (unsigned short*)alloc((size_t)E_ * 16 * F_ * 2);
  unsigned short* xguP  = (unsigned short*)alloc((size_t)T_ * NCAT * 2);  // 69.2 MB
  unsigned short* hq    = (unsigned short*)alloc((size_t)T_ * KH * 2);
  float* Qpart          = (float*)alloc((size_t)16 * T_ * 32 * 4);
  int* bucketTok        = (int*)alloc((size_t)64 * T_ * 4);
  int* bucketCnt        = (int*)alloc((size_t)64 * 4);
  int* tileList         = (int*)alloc((size_t)NTILE_MAX * 4);
  int2* topi            = (int2*)alloc((size_t)T_ * 8);
  float2* topw          = (float2*)alloc((size_t)T_ * 8);
  // Opart (2 strips x 16.7 MB f32 = 33.5 MB) ALIASES xguP (69.2 MB): xguP is dead
  // after s3d; stream order s3d -> qscatter -> gemm2 -> sum2 makes the reuse race-free.
  float* Opart          = (float*)xguP;

  conv_kernel<<<dim3(2048, 5), 256, 0, stream>>>(x, W1, W3, W2, A1, A3, B1, B3, A2, B2,
                                                 xb, Wcatb, W2cat, B1b, B3b, A2r);
  router_kernel<<<dim3(1024), 256, 0, stream>>>(x, gw, logits, topi, topw);
  bucket_kernel<<<dim3(64), 256, 0, stream>>>(topi, bucketTok, bucketCnt);
  tilelist_kernel<<<dim3(1), 64, 0, stream>>>(bucketCnt, tileList);
  // gemm1: xguP = xb @ Wcat^T   [4096 x 8448], K=1024  (3-buffer depth-2 prefetch)
  gemm1_3b<<<dim3(32 * 66), 256, 0, stream>>>(xb, Wcatb, xguP, T_, NCAT, 1024, 32);
  // s3d: SwiGLU + LoRA-B + q-contraction fused (writes hq cols 0..4095 + 16 Qpart strips)
  s3d_kernel<<<dim3(NTILE_MAX, 4), 256, 0, stream>>>(xguP, B1b, B3b, A2r, bucketTok,
                                                     bucketCnt, topw, tileList, hq, Qpart);
  // qscatter: hq cols 4096..4223 = route-expanded Q (zeros elsewhere)
  qscatter_kernel<<<dim3(2048), 256, 0, stream>>>(Qpart, topi, hq);
  // gemm2: Opart[z] = hq @ W2cat^T (K-chunk z)  [4096 x 1024], K=4224 split 2x2112,
  // 128x128 tile -> grid (32*8, 1, 2) = 512 blocks (2 per CU)
  gemm_bt<128, float><<<dim3(32 * 8, 1, 2), 256, 0, stream>>>(
      hq, W2cat, Opart, T_, D_, KH, 2112, 32);
  sum2_kernel<<<dim3(4096), 256, 0, stream>>>(Opart, out);
}

// Round 18
// 239.812 us; speedup vs baseline: 1.1406x; 1.1406x over previous
//
#include <hip/hip_runtime.h>
#include <stdint.h>

#define T_ 4096
#define D_ 1024
#define F_ 4096
#define E_ 8
#define NCAT 8448   // 4096 (gate) + 4096 (up) + 256 (2*A1cat | 2*A3cat rows)
#define KH 4224     // hsum K (4096) + route-expanded Q (128)
#define NTILE_MAX 320

typedef __attribute__((ext_vector_type(8))) short          s16x8;
typedef __attribute__((ext_vector_type(8))) unsigned short u16x8;
typedef __attribute__((ext_vector_type(4))) unsigned short u16x4;
typedef __attribute__((ext_vector_type(4))) float          f32x4;

__device__ __forceinline__ unsigned short f2bf(float f) {
  unsigned u = __float_as_uint(f);
  u += 0x7fffu + ((u >> 16) & 1u);   // round-to-nearest-even
  return (unsigned short)(u >> 16);
}
__device__ __forceinline__ float b2f(unsigned short h) {
  return __uint_as_float(((unsigned)h) << 16);
}

// ---------------------------------------------------------------- convert
__device__ __forceinline__ void cvt8(const float* __restrict__ s, unsigned short* __restrict__ d) {
  float4 a = *(const float4*)s;
  float4 b = *(const float4*)(s + 4);
  u16x8 v;
  v[0] = f2bf(a.x); v[1] = f2bf(a.y); v[2] = f2bf(a.z); v[3] = f2bf(a.w);
  v[4] = f2bf(b.x); v[5] = f2bf(b.y); v[6] = f2bf(b.z); v[7] = f2bf(b.w);
  *(u16x8*)d = v;
}
__device__ __forceinline__ void cvt8s2(const float* __restrict__ s, unsigned short* __restrict__ d) {
  float4 a = *(const float4*)s;
  float4 b = *(const float4*)(s + 4);
  u16x8 v;
  v[0] = f2bf(2.f * a.x); v[1] = f2bf(2.f * a.y); v[2] = f2bf(2.f * a.z); v[3] = f2bf(2.f * a.w);
  v[4] = f2bf(2.f * b.x); v[5] = f2bf(2.f * b.y); v[6] = f2bf(2.f * b.z); v[7] = f2bf(2.f * b.w);
  *(u16x8*)d = v;
}

__global__ __launch_bounds__(256) void conv_kernel(
    const float* __restrict__ x,  const float* __restrict__ W1,
    const float* __restrict__ W3, const float* __restrict__ W2,
    const float* __restrict__ A1, const float* __restrict__ A3,
    const float* __restrict__ B1, const float* __restrict__ B3,
    const float* __restrict__ A2, const float* __restrict__ B2,
    unsigned short* __restrict__ xb,  unsigned short* __restrict__ Wcatb,
    unsigned short* __restrict__ W2cat, unsigned short* __restrict__ B1b,
    unsigned short* __restrict__ B3b, unsigned short* __restrict__ A2r) {
  const int y = blockIdx.y;
  const size_t i0 = ((size_t)blockIdx.x * 256 + threadIdx.x) * 8;
  if (y == 0) { cvt8(x + i0, xb + i0); }
  else if (y == 1) {
    // W2 [1024][4096] -> W2cat rows of stride 4224 (cols 0..4095)
    const size_t d = i0 >> 12, f = i0 & 4095;
    cvt8(W2 + i0, W2cat + d * KH + f);
  }
  else if (y == 2) { cvt8(W1 + i0, Wcatb + i0); }
  else if (y == 3) { cvt8(W3 + i0, Wcatb + 4194304 + i0); }
  else {
    // small tensors, 8-wide. SCALE=2 folded into A-matrices. 245760 groups of 8.
    const size_t o8 = (size_t)blockIdx.x * 256 + threadIdx.x;
    if (o8 < 245760) {
      const size_t o = o8 * 8;
      if (o < 131072)        cvt8s2(A1 + o, Wcatb + 8388608 + o);
      else if (o < 262144)   cvt8s2(A3 + (o - 131072), Wcatb + 8388608 + o);
      else if (o < 786432)   cvt8(B1 + (o - 262144), B1b + (o - 262144));
      else if (o < 1310720)  cvt8(B3 + (o - 786432), B3b + (o - 786432));
      else if (o < 1835008)  cvt8s2(A2 + (o - 1310720), A2r + (o - 1310720)); // [E][16][F]
      else {
        // B2cat: W2cat[d][4096 + e*16 + r] = B2[e][d][r]  (plain, no scale)
        const size_t oo = o - 1835008;              // 131072 = 1024*128
        const size_t d = oo >> 7, j = oo & 127;
        const size_t e = j >> 4, r0 = j & 15;       // r0 in {0,8}
        cvt8(B2 + e * ((size_t)D_ * 16) + d * 16 + r0, W2cat + d * KH + 4096 + j);
      }
    }
  }
}

// ---------------------------------------------------------------- router
__global__ __launch_bounds__(256) void router_kernel(
    const float* __restrict__ x, const float* __restrict__ gw,
    float* __restrict__ logits, int2* __restrict__ topi, float2* __restrict__ topw) {
  const int wave = threadIdx.x >> 6, lane = threadIdx.x & 63;
  const int t = blockIdx.x * 4 + wave;
  const float* xr = x + (size_t)t * D_;
  float acc[E_] = {0, 0, 0, 0, 0, 0, 0, 0};
  for (int it = 0; it < 16; ++it) {
    const int d = lane + it * 64;
    const float xv = xr[d];
#pragma unroll
    for (int e = 0; e < E_; ++e) acc[e] += xv * gw[e * D_ + d];
  }
#pragma unroll
  for (int e = 0; e < E_; ++e)
#pragma unroll
    for (int m = 1; m < 64; m <<= 1) acc[e] += __shfl_xor(acc[e], m);
  if (lane == 0) {
    float m0v = acc[0]; int m0i = 0;
#pragma unroll
    for (int e = 1; e < E_; ++e) if (acc[e] > m0v) { m0v = acc[e]; m0i = e; }
    float m1v = -3.0e38f; int m1i = 0;
#pragma unroll
    for (int e = 0; e < E_; ++e) if (e != m0i && acc[e] > m1v) { m1v = acc[e]; m1i = e; }
    const float e1 = __expf(m1v - m0v);
    const float inv = 1.f / (1.f + e1);
    topi[t] = make_int2(m0i, m1i);
    topw[t] = make_float2(inv, e1 * inv);
#pragma unroll
    for (int e = 0; e < E_; ++e) logits[(size_t)t * E_ + e] = acc[e];
  }
}

// ---------------------------------------------------------------- pair buckets
__global__ __launch_bounds__(256) void bucket_kernel(
    const int2* __restrict__ topi, int* __restrict__ bucketTok, int* __restrict__ bucketCnt) {
  const int pid = blockIdx.x;
  const int e0 = pid >> 3, e1 = pid & 7;
  __shared__ int cnt;
  if (threadIdx.x == 0) cnt = 0;
  __syncthreads();
  for (int t = threadIdx.x; t < T_; t += 256) {
    const int2 ti = topi[t];
    if (ti.x == e0 && ti.y == e1) {
      const int s = atomicAdd(&cnt, 1);
      bucketTok[pid * T_ + s] = t;
    }
  }
  __syncthreads();
  if (threadIdx.x == 0) bucketCnt[pid] = cnt;
}

// ---------------------------------------------------------------- compact tile worklist (wave prefix scan)
__global__ void tilelist_kernel(const int* __restrict__ bucketCnt, int* __restrict__ tileList) {
  const int pid = threadIdx.x;  // 64 threads, 1 wave
  const int ntile = (bucketCnt[pid] + 15) >> 4;
  int scan = ntile;
#pragma unroll
  for (int m = 1; m < 64; m <<= 1) {
    const int v = __shfl_up(scan, m);
    if (pid >= m) scan += v;
  }
  const int base = scan - ntile;
  const int total = __shfl(scan, 63);
  for (int i = 0; i < ntile; ++i) tileList[base + i] = (pid << 16) | i;
  for (int i = total + pid; i < NTILE_MAX; i += 64) tileList[i] = -1;
}

__device__ __forceinline__ void cstore(float* C, size_t i, float v) { C[i] = v; }
__device__ __forceinline__ void cstore(unsigned short* C, size_t i, float v) { C[i] = f2bf(v); }

#define GLL(g, l) __builtin_amdgcn_global_load_lds(                            \
    (const __attribute__((address_space(1))) void*)(g),                       \
    (__attribute__((address_space(3))) void*)(l), 16, 0, 0)

// ---------------------------------------------------------------- GEMM: 2-phase double-buffered (proven, 687 TF at 128 tile)
// Optional K-split via blockIdx.z (Kstride = row stride, ksub = per-z K chunk).
template <int BN, typename OUT_T>
__global__ __launch_bounds__(256) void gemm_bt(
    const unsigned short* __restrict__ A, const unsigned short* __restrict__ B,
    OUT_T* __restrict__ C, int M, int N, int Kstride, int ksub, int nbx) {
  constexpr int WCOL = BN / 2, NF = WCOL / 16;
  constexpr int BITER = BN / 32;
  __shared__ __align__(16) char As[2 * 16384];
  __shared__ __align__(16) char Bs[2 * BN * 128];
  const int tid = threadIdx.x;
  int bid = blockIdx.x;
  bid = (bid & 7) * (gridDim.x >> 3) + (bid >> 3);  // XCD swizzle (grid %8==0)
  const int bx = bid % nbx, by = bid / nbx;
  const long m0 = (long)bx * 128, n0 = (long)by * BN;
  const int k0 = blockIdx.z * ksub;
  C += (size_t)blockIdx.z * M * N;                  // K-split partial strip

  const unsigned short* asrc[4];
  const unsigned short* bsrc[BITER];
#pragma unroll
  for (int i = 0; i < 4; ++i) {
    const int g = i * 256 + tid, row = g >> 3, cb = (g & 7) ^ (row & 7);
    asrc[i] = A + (m0 + row) * (size_t)Kstride + k0 + cb * 8;
  }
#pragma unroll
  for (int i = 0; i < BITER; ++i) {
    const int g = i * 256 + tid, row = g >> 3, cb = (g & 7) ^ (row & 7);
    bsrc[i] = B + (n0 + row) * (size_t)Kstride + k0 + cb * 8;
  }
  const int lane = tid & 63, wave = tid >> 6;
  const int wr = wave >> 1, wc = wave & 1;
  const int wb = (tid & 192) * 16;
  int aoff[4][2], boff[NF][2];
#pragma unroll
  for (int mf = 0; mf < 4; ++mf) {
    const int ra = wr * 64 + mf * 16 + (lane & 15);
#pragma unroll
    for (int ks = 0; ks < 2; ++ks) {
      const int kb = (ks * 32 + (lane >> 4) * 8) * 2;
      aoff[mf][ks] = (ra * 128 + kb) ^ ((ra & 7) << 4);
    }
  }
#pragma unroll
  for (int nf = 0; nf < NF; ++nf) {
    const int rb = wc * WCOL + nf * 16 + (lane & 15);
#pragma unroll
    for (int ks = 0; ks < 2; ++ks) {
      const int kb = (ks * 32 + (lane >> 4) * 8) * 2;
      boff[nf][ks] = (rb * 128 + kb) ^ ((rb & 7) << 4);
    }
  }

  auto STAGE = [&](int buf, int kt) {
    const size_t ko = (size_t)kt * 64;
#pragma unroll
    for (int i = 0; i < 4; ++i) GLL(asrc[i] + ko, As + buf * 16384 + i * 4096 + wb);
#pragma unroll
    for (int i = 0; i < BITER; ++i) GLL(bsrc[i] + ko, Bs + buf * (BN * 128) + i * 4096 + wb);
  };

  f32x4 acc[4][NF] = {};
  const int nk = ksub >> 6;
  int cur = 0;
  STAGE(0, 0);
  asm volatile("s_waitcnt vmcnt(0)" ::: "memory");
  __builtin_amdgcn_s_barrier();
  for (int kt = 0; kt < nk; ++kt) {
    if (kt + 1 < nk) STAGE(cur ^ 1, kt + 1);
    const char* Ab = As + cur * 16384;
    const char* Bb = Bs + cur * (BN * 128);
#pragma unroll
    for (int ks = 0; ks < 2; ++ks) {
      s16x8 af[4], bfv[NF];
#pragma unroll
      for (int mf = 0; mf < 4; ++mf) af[mf] = *(const s16x8*)(Ab + aoff[mf][ks]);
#pragma unroll
      for (int nf = 0; nf < NF; ++nf) bfv[nf] = *(const s16x8*)(Bb + boff[nf][ks]);
#pragma unroll
      for (int mf = 0; mf < 4; ++mf)
#pragma unroll
        for (int nf = 0; nf < NF; ++nf)
          acc[mf][nf] = __builtin_amdgcn_mfma_f32_16x16x32_bf16(af[mf], bfv[nf], acc[mf][nf], 0, 0, 0);
    }
    asm volatile("s_waitcnt vmcnt(0)" ::: "memory");
    __builtin_amdgcn_s_barrier();
    cur ^= 1;
  }
#pragma unroll
  for (int mf = 0; mf < 4; ++mf) {
    const int row0 = (int)m0 + wr * 64 + mf * 16 + ((lane >> 4) << 2);
#pragma unroll
    for (int nf = 0; nf < NF; ++nf) {
      const long col = n0 + wc * WCOL + nf * 16 + (lane & 15);
#pragma unroll
      for (int q = 0; q < 4; ++q)
        cstore(C, (size_t)(row0 + q) * N + col, acc[mf][nf][q]);
    }
  }
}

// ---------------------------------------------------------------- s3d: fused SwiGLU + LoRA-B + q-contraction (operand-swapped MFMA)
__global__ __launch_bounds__(256) void s3d_kernel(
    const unsigned short* __restrict__ xguP,  // [T, NCAT]
    const unsigned short* __restrict__ B1b,   // [E][F][16] bf16
    const unsigned short* __restrict__ B3b,   // [E][F][16] bf16
    const unsigned short* __restrict__ A2r,   // [E][16][F] bf16 (pre-scaled 2x)
    const int* __restrict__ bucketTok, const int* __restrict__ bucketCnt,
    const float2* __restrict__ topw, const int* __restrict__ tileList,
    unsigned short* __restrict__ hq,          // [T][KH] bf16 (cols 0..4095 = hsum)
    float* __restrict__ Qpart) {              // [16][T][32]  (strip = quarter*4 + wave)
  const int entry = tileList[blockIdx.x];
  if (entry < 0) return;
  const int pid = entry >> 16, z = entry & 0xffff;
  const int nt = bucketCnt[pid];
  const int e0 = pid >> 3, e1 = pid & 7;

  __shared__ int   ldsTok[16];
  __shared__ float ldsW[2][16];
  __shared__ __align__(16) unsigned short hwT[4][2][16][40];  // [wave][expert][token][f pad 32->40]
  const int tid = threadIdx.x;
  if (tid < 16) {
    int s = z * 16 + tid; if (s >= nt) s = nt - 1;
    const int t = bucketTok[pid * T_ + s];
    ldsTok[tid] = t;
    const float2 w = topw[t];
    ldsW[0][tid] = w.x; ldsW[1][tid] = w.y;
  }
  __syncthreads();

  const int lane = tid & 63, wave = tid >> 6;
  const int col = lane & 15, chunk = lane >> 4;

  const int t = ldsTok[col];
  const float w0 = ldsW[0][col], w1 = ldsW[1][col];
  const unsigned short* abase = xguP + (size_t)t * NCAT + 8192 +
                                (chunk >> 1) * 128 + (chunk & 1) * 8;
  const s16x8 afrag0 = *(const s16x8*)(abase + e0 * 16);
  const s16x8 afrag1 = *(const s16x8*)(abase + e1 * 16);

  unsigned short (*hw_w)[16][40] = hwT[wave];
  f32x4 qacc0 = {}, qacc1 = {};
  const int ft0 = blockIdx.y * 64 + wave * 16;   // 16 f-tiles per wave

  for (int p = 0; p < 8; ++p) {                  // pairs of 16-f subtiles (K=32 for q-MFMA)
#pragma unroll
    for (int half = 0; half < 2; ++half) {
      const int i = p * 2 + half;
      const int fcol = (ft0 + i) * 16 + col;     // A-operand (B1/B3) row = f position = lane&15
      s16x8 bg0 = {}, bu0 = {}, bg1 = {}, bu1 = {};
      if (chunk < 2) {
        bg0 = *(const s16x8*)(B1b + ((size_t)e0 * F_ + fcol) * 16 + chunk * 8);
        bg1 = *(const s16x8*)(B1b + ((size_t)e1 * F_ + fcol) * 16 + chunk * 8);
      } else {
        bu0 = *(const s16x8*)(B3b + ((size_t)e0 * F_ + fcol) * 16 + (chunk - 2) * 8);
        bu1 = *(const s16x8*)(B3b + ((size_t)e1 * F_ + fcol) * 16 + (chunk - 2) * 8);
      }
      f32x4 accg0 = {}, accu0 = {}, accg1 = {}, accu1 = {};
      accg0 = __builtin_amdgcn_mfma_f32_16x16x32_bf16(bg0, afrag0, accg0, 0, 0, 0);
      accu0 = __builtin_amdgcn_mfma_f32_16x16x32_bf16(bu0, afrag0, accu0, 0, 0, 0);
      accg1 = __builtin_amdgcn_mfma_f32_16x16x32_bf16(bg1, afrag1, accg1, 0, 0, 0);
      accu1 = __builtin_amdgcn_mfma_f32_16x16x32_bf16(bu1, afrag1, accu1, 0, 0, 0);

      const int fbase = (ft0 + i) * 16 + chunk * 4;   // 4 consecutive f for q=0..3
      const u16x4 xgv = *(const u16x4*)(xguP + (size_t)t * NCAT + fbase);
      const u16x4 xuv = *(const u16x4*)(xguP + (size_t)t * NCAT + 4096 + fbase);
      u16x4 hqv, h0v, h1v;
#pragma unroll
      for (int q = 0; q < 4; ++q) {
        const float xg = b2f(xgv[q]);
        const float xu = b2f(xuv[q]);
        const float g0 = xg + accg0[q], u0 = xu + accu0[q];
        const float g1 = xg + accg1[q], u1 = xu + accu1[q];
        const float h0 = g0 * u0 * __builtin_amdgcn_rcpf(1.f + __expf(-g0));  // silu via rcp (~1ulp)
        const float h1 = g1 * u1 * __builtin_amdgcn_rcpf(1.f + __expf(-g1));
        const unsigned short hb0 = f2bf(w0 * h0);
        const unsigned short hb1 = f2bf(w1 * h1);
        h0v[q] = hb0; h1v[q] = hb1;
        hqv[q] = f2bf(b2f(hb0) + b2f(hb1));
      }
      *(u16x4*)(hq + (size_t)t * KH + fbase) = hqv;
      *(u16x4*)&hw_w[0][col][half * 16 + chunk * 4] = h0v;  // LDS transpose stage
      *(u16x4*)&hw_w[1][col][half * 16 + chunk * 4] = h1v;
    }
    // wave-private region: writes above -> reads below (RAW via lgkmcnt; DS in-order per wave)
    asm volatile("s_waitcnt lgkmcnt(0)" ::: "memory");
    const s16x8 hf0 = *(const s16x8*)&hw_w[0][lane & 15][(lane >> 4) * 8];
    const s16x8 hf1 = *(const s16x8*)&hw_w[1][lane & 15][(lane >> 4) * 8];
    const int fb = (ft0 + 2 * p) * 16 + (lane >> 4) * 8;
    const s16x8 a2f0 = *(const s16x8*)(A2r + ((size_t)e0 * 16 + (lane & 15)) * F_ + fb);
    const s16x8 a2f1 = *(const s16x8*)(A2r + ((size_t)e1 * 16 + (lane & 15)) * F_ + fb);
    qacc0 = __builtin_amdgcn_mfma_f32_16x16x32_bf16(hf0, a2f0, qacc0, 0, 0, 0);
    qacc1 = __builtin_amdgcn_mfma_f32_16x16x32_bf16(hf1, a2f1, qacc1, 0, 0, 0);
  }

  const int r = lane & 15;
  float* qp = Qpart + ((size_t)blockIdx.y * 4 + wave) * T_ * 32;
#pragma unroll
  for (int q = 0; q < 4; ++q) {
    const int tq = ldsTok[chunk * 4 + q];
    qp[(size_t)tq * 32 + r]      = qacc0[q];
    qp[(size_t)tq * 32 + 16 + r] = qacc1[q];
  }
}

// ---------------------------------------------------------------- qscatter: hq[t][4096+j] = route-expanded sum of Qpart strips
__global__ __launch_bounds__(256) void qscatter_kernel(
    const float* __restrict__ Qpart, const int2* __restrict__ topi,
    unsigned short* __restrict__ hq) {
  const int gid = blockIdx.x * 256 + threadIdx.x;   // 524288 = T * 128
  const int t = gid >> 7, j = gid & 127;
  const int2 ti = topi[t];
  const int eb = j >> 4, r = j & 15;
  float v = 0.f;
  if (eb == ti.x) {
#pragma unroll
    for (int st = 0; st < 16; ++st) v += Qpart[(size_t)st * (T_ * 32) + t * 32 + r];
  } else if (eb == ti.y) {
#pragma unroll
    for (int st = 0; st < 16; ++st) v += Qpart[(size_t)st * (T_ * 32) + t * 32 + 16 + r];
  }
  hq[(size_t)t * KH + 4096 + j] = f2bf(v);
}

// ---------------------------------------------------------------- sum2: out = Opart[0] + Opart[1]  (float4)
__global__ __launch_bounds__(256) void sum2_kernel(const float* __restrict__ Op,
                                                   float* __restrict__ out) {
  const size_t i = ((size_t)blockIdx.x * 256 + threadIdx.x) * 4;
  const float4 a = *(const float4*)(Op + i);
  const float4 b = *(const float4*)(Op + (size_t)T_ * D_ + i);
  float4 o;
  o.x = a.x + b.x; o.y = a.y + b.y; o.z = a.z + b.z; o.w = a.w + b.w;
  *(float4*)(out + i) = o;
}

// ---------------------------------------------------------------- launcher
extern "C" void kernel_launch(void* const* d_in, const int* in_sizes, int n_in,
                              void* d_out, int out_size, void* d_ws, size_t ws_size,
                              hipStream_t stream) {
  (void)in_sizes; (void)n_in; (void)out_size; (void)ws_size;
  const float* x   = (const float*)d_in[0];
  const float* gw  = (const float*)d_in[1];
  const float* W1  = (const float*)d_in[2];
  const float* W3  = (const float*)d_in[3];
  const float* W2  = (const float*)d_in[4];
  const float* A1  = (const float*)d_in[5];
  const float* B1  = (const float*)d_in[6];
  const float* A3  = (const float*)d_in[7];
  const float* B3  = (const float*)d_in[8];
  const float* A2  = (const float*)d_in[9];
  const float* B2  = (const float*)d_in[10];
  float* out = (float*)d_out;
  float* logits = out + (size_t)T_ * D_;

  char* w = (char*)d_ws;
  auto alloc = [&](size_t bytes) { char* p = w; w += (bytes + 255) & ~(size_t)255; return p; };
  unsigned short* xb    = (unsigned short*)alloc((size_t)T_ * D_ * 2);
  unsigned short* Wcatb = (unsigned short*)alloc((size_t)NCAT * D_ * 2);
  unsigned short* W2cat = (unsigned short*)alloc((size_t)D_ * KH * 2);
  unsigned short* B1b   = (unsigned short*)alloc((size_t)E_ * F_ * 16 * 2);
  unsigned short* B3b   = (unsigned short*)alloc((size_t)E_ * F_ * 16 * 2);
  unsigned short* A2r   = (unsigned short*)alloc((size_t)E_ * 16 * F_ * 2);
  unsigned short* xguP  = (unsigned short*)alloc((size_t)T_ * NCAT * 2);  // 69.2 MB
  unsigned short* hq    = (unsigned short*)alloc((size_t)T_ * KH * 2);
  float* Qpart          = (float*)alloc((size_t)16 * T_ * 32 * 4);
  int* bucketTok        = (int*)alloc((size_t)64 * T_ * 4);
  int* bucketCnt        = (int*)alloc((size_t)64 * 4);
  int* tileList         = (int*)alloc((size_t)NTILE_MAX * 4);
  int2* topi            = (int2*)alloc((size_t)T_ * 8);
  float2* topw          = (float2*)alloc((size_t)T_ * 8);
  // Opart (2 strips x 16.7 MB f32 = 33.5 MB) ALIASES xguP (69.2 MB): xguP is dead
  // after s3d; stream order s3d -> qscatter -> gemm2 -> sum2 makes the reuse race-free.
  float* Opart          = (float*)xguP;

  conv_kernel<<<dim3(2048, 5), 256, 0, stream>>>(x, W1, W3, W2, A1, A3, B1, B3, A2, B2,
                                                 xb, Wcatb, W2cat, B1b, B3b, A2r);
  router_kernel<<<dim3(1024), 256, 0, stream>>>(x, gw, logits, topi, topw);
  bucket_kernel<<<dim3(64), 256, 0, stream>>>(topi, bucketTok, bucketCnt);
  tilelist_kernel<<<dim3(1), 64, 0, stream>>>(bucketCnt, tileList);
  // gemm1: xguP = xb @ Wcat^T   [4096 x 8448], K=1024  (proven 2-phase, 687 TF)
  gemm_bt<128, unsigned short><<<dim3(32 * 66, 1, 1), 256, 0, stream>>>(
      xb, Wcatb, xguP, T_, NCAT, 1024, 1024, 32);
  // s3d: SwiGLU + LoRA-B + q-contraction fused (writes hq cols 0..4095 + 16 Qpart strips)
  s3d_kernel<<<dim3(NTILE_MAX, 4), 256, 0, stream>>>(xguP, B1b, B3b, A2r, bucketTok,
                                                     bucketCnt, topw, tileList, hq, Qpart);
  // qscatter: hq cols 4096..4223 = route-expanded Q (zeros elsewhere)
  qscatter_kernel<<<dim3(2048), 256, 0, stream>>>(Qpart, topi, hq);
  // gemm2: Opart[z] = hq @ W2cat^T (K-chunk z)  [4096 x 1024], K=4224 split 2x2112,
  // 128x128 tile -> grid (32*8, 1, 2) = 512 blocks (2 per CU)
  gemm_bt<128, float><<<dim3(32 * 8, 1, 2), 256, 0, stream>>>(
      hq, W2cat, Opart, T_, D_, KH, 2112, 32);
  sum2_kernel<<<dim3(4096), 256, 0, stream>>>(Opart, out);
}